// Round 1
// baseline (357.121 us; speedup 1.0000x reference)
//
#include <hip/hip_runtime.h>

// ---------------- problem constants ----------------
constexpr int NTOK = 4096;    // B*S
constexpr int DIM  = 512;     // D
constexpr int FF   = 1536;    // F
constexpr int NE   = 8;       // experts
constexpr int CAP  = 4096;    // per-expert list capacity (worst case)

typedef __attribute__((ext_vector_type(8))) short short8;   // 8 bf16 = 4 VGPR
typedef __attribute__((ext_vector_type(4))) float f32x4;    // MFMA acc

static __device__ __forceinline__ unsigned short f2bf(float f) {
    unsigned int x = __float_as_uint(f);
    unsigned int r = x + 0x7fffu + ((x >> 16) & 1u);   // RNE
    return (unsigned short)(r >> 16);
}

// ---------------- router: logits, top-2, softmax, scatter lists ----------------
__global__ __launch_bounds__(256) void moe_router(
    const float* __restrict__ x, const float* __restrict__ wg,
    int* __restrict__ cnt, int* __restrict__ lists, float* __restrict__ wts)
{
    int lane = threadIdx.x & 63;
    int wave = threadIdx.x >> 6;
    int tok  = blockIdx.x * 4 + wave;
    if (tok >= NTOK) return;

    float acc[NE];
#pragma unroll
    for (int e = 0; e < NE; ++e) acc[e] = 0.f;

    const float* xr = x + (size_t)tok * DIM;
#pragma unroll
    for (int i = 0; i < DIM / 64; ++i) {
        int d = i * 64 + lane;
        float xv = xr[d];
        const float4* wr = (const float4*)(wg + (size_t)d * NE);
        float4 w0 = wr[0], w1 = wr[1];
        acc[0] += xv * w0.x; acc[1] += xv * w0.y; acc[2] += xv * w0.z; acc[3] += xv * w0.w;
        acc[4] += xv * w1.x; acc[5] += xv * w1.y; acc[6] += xv * w1.z; acc[7] += xv * w1.w;
    }
#pragma unroll
    for (int e = 0; e < NE; ++e) {
#pragma unroll
        for (int off = 32; off >= 1; off >>= 1)
            acc[e] += __shfl_xor(acc[e], off, 64);
    }
    if (lane == 0) {
        int i0 = 0; float m0 = acc[0];
#pragma unroll
        for (int e = 1; e < NE; ++e) if (acc[e] > m0) { m0 = acc[e]; i0 = e; }
        int i1 = -1; float m1 = -3.4e38f;
#pragma unroll
        for (int e = 0; e < NE; ++e) if (e != i0 && acc[e] > m1) { m1 = acc[e]; i1 = e; }
        float e1 = expf(m1 - m0);
        float s  = 1.f + e1;
        float w0v = 1.f / s, w1v = e1 / s;
        int s0 = tok * 2, s1 = tok * 2 + 1;
        wts[s0] = w0v;
        wts[s1] = w1v;
        int p0 = atomicAdd(&cnt[i0], 1);
        lists[i0 * CAP + p0] = s0;
        int p1 = atomicAdd(&cnt[i1], 1);
        lists[i1 * CAP + p1] = s1;
    }
}

// ---------------- transpose fp32 [R][C] -> bf16 [C][R], per expert (z) ----------------
__global__ __launch_bounds__(256) void transpose_cvt(
    const float* __restrict__ in, unsigned short* __restrict__ out, int R, int C)
{
    __shared__ float tile[64][65];
    int c0 = blockIdx.x * 64;
    int r0 = blockIdx.y * 64;
    int z  = blockIdx.z;
    const float* ip = in + (size_t)z * R * C;
    unsigned short* op = out + (size_t)z * R * C;

    int tr = threadIdx.x >> 4;          // 0..15
    int tc = (threadIdx.x & 15) * 4;    // 0,4,..,60
#pragma unroll
    for (int p = 0; p < 4; ++p) {
        int r = p * 16 + tr;
        float4 v = *(const float4*)(ip + (size_t)(r0 + r) * C + c0 + tc);
        tile[r][tc + 0] = v.x; tile[r][tc + 1] = v.y;
        tile[r][tc + 2] = v.z; tile[r][tc + 3] = v.w;
    }
    __syncthreads();
#pragma unroll
    for (int p = 0; p < 4; ++p) {
        int c = p * 16 + tr;            // output row = original col
        ushort4 o;
        o.x = f2bf(tile[tc + 0][c]);
        o.y = f2bf(tile[tc + 1][c]);
        o.z = f2bf(tile[tc + 2][c]);
        o.w = f2bf(tile[tc + 3][c]);
        *(ushort4*)(op + (size_t)(c0 + c) * R + r0 + tc) = o;
    }
}

// ---------------- FFN1: act[slot][f] = silu(x W1) * (x W3 + b3), grouped by expert ----------------
__global__ __launch_bounds__(256) void moe_ffn1(
    const float* __restrict__ x,
    const unsigned short* __restrict__ w1t,   // [E][F][D] bf16
    const unsigned short* __restrict__ w3t,   // [E][F][D] bf16
    const float* __restrict__ b3,             // [E][F]
    const int* __restrict__ cnt, const int* __restrict__ lists,
    unsigned short* __restrict__ act)         // [2*NTOK][F] bf16
{
    int e    = blockIdx.y >> 6;
    int mb   = blockIdx.y & 63;
    int n0   = blockIdx.x * 64;               // f tile base
    int ce   = cnt[e];
    int row0 = mb * 64;
    if (row0 >= ce) return;

    __shared__ int  s_slot[64];
    __shared__ char sA [64 * 128];
    __shared__ char sB1[64 * 128];
    __shared__ char sB3[64 * 128];

    int tid = threadIdx.x;
    if (tid < 64) {
        int r = row0 + tid;
        s_slot[tid] = (r < ce) ? lists[e * CAP + r] : lists[e * CAP + row0];
    }
    __syncthreads();

    int lane = tid & 63;
    int wv   = tid >> 6;
    int wm   = wv >> 1, wn = wv & 1;          // 2x2 waves -> 32x32 each

    f32x4 acch[2][2], accg[2][2];
#pragma unroll
    for (int i = 0; i < 2; ++i)
#pragma unroll
        for (int j = 0; j < 2; ++j) { acch[i][j] = (f32x4)0.f; accg[i][j] = (f32x4)0.f; }

    int lr = tid >> 2;        // staging row 0..63
    int lq = tid & 3;         // staging quad

    int tokr = s_slot[lr] >> 1;
    const float*          xr  = x   + (size_t)tokr * DIM;
    const unsigned short* w1p = w1t + ((size_t)e * FF + n0 + lr) * DIM;
    const unsigned short* w3p = w3t + ((size_t)e * FF + n0 + lr) * DIM;

    for (int kc = 0; kc < DIM; kc += 64) {
        // A: gathered x rows, fp32 -> bf16, XOR-swizzled
#pragma unroll
        for (int j = 0; j < 4; ++j) {
            int dl = lq * 16 + j * 4;
            float4 v = *(const float4*)(xr + kc + dl);
            ushort4 o;
            o.x = f2bf(v.x); o.y = f2bf(v.y); o.z = f2bf(v.z); o.w = f2bf(v.w);
            int ba = (lr * 128 + dl * 2) ^ ((lr & 7) << 4);
            *(ushort4*)(sA + ba) = o;
        }
        // B1, B3: already bf16 (B^T layout), 16B loads
#pragma unroll
        for (int h = 0; h < 2; ++h) {
            int dl = lq * 16 + h * 8;
            int ba = (lr * 128 + dl * 2) ^ ((lr & 7) << 4);
            *(short8*)(sB1 + ba) = *(const short8*)(w1p + kc + dl);
            *(short8*)(sB3 + ba) = *(const short8*)(w3p + kc + dl);
        }
        __syncthreads();

#pragma unroll
        for (int ks = 0; ks < 2; ++ks) {
            short8 af[2], b1f[2], b3f[2];
#pragma unroll
            for (int mi = 0; mi < 2; ++mi) {
                int row = wm * 32 + mi * 16 + (lane & 15);
                int ba  = (row * 128 + ks * 64 + (lane >> 4) * 16) ^ ((row & 7) << 4);
                af[mi] = *(const short8*)(sA + ba);
            }
#pragma unroll
            for (int ni = 0; ni < 2; ++ni) {
                int row = wn * 32 + ni * 16 + (lane & 15);
                int ba  = (row * 128 + ks * 64 + (lane >> 4) * 16) ^ ((row & 7) << 4);
                b1f[ni] = *(const short8*)(sB1 + ba);
                b3f[ni] = *(const short8*)(sB3 + ba);
            }
#pragma unroll
            for (int mi = 0; mi < 2; ++mi)
#pragma unroll
                for (int ni = 0; ni < 2; ++ni) {
                    acch[mi][ni] = __builtin_amdgcn_mfma_f32_16x16x32_bf16(af[mi], b1f[ni], acch[mi][ni], 0, 0, 0);
                    accg[mi][ni] = __builtin_amdgcn_mfma_f32_16x16x32_bf16(af[mi], b3f[ni], accg[mi][ni], 0, 0, 0);
                }
        }
        __syncthreads();
    }

    // epilogue: act = silu(h) * (g + b3)
#pragma unroll
    for (int ni = 0; ni < 2; ++ni) {
        int fcol = n0 + wn * 32 + ni * 16 + (lane & 15);
        float b3v = b3[e * FF + fcol];
#pragma unroll
        for (int mi = 0; mi < 2; ++mi) {
            int rl = wm * 32 + mi * 16 + (lane >> 4) * 4;
#pragma unroll
            for (int r = 0; r < 4; ++r) {
                int rg = rl + r;
                if (row0 + rg < ce) {
                    float h = acch[mi][ni][r];
                    float g = accg[mi][ni][r] + b3v;
                    float a = (h / (1.f + __expf(-h))) * g;
                    int slot = s_slot[rg];
                    act[(size_t)slot * FF + fcol] = f2bf(a);
                }
            }
        }
    }
}

// ---------------- FFN2: yws[slot][d] = w_slot * (act W2), grouped by expert ----------------
__global__ __launch_bounds__(256) void moe_ffn2(
    const unsigned short* __restrict__ act,   // [2*NTOK][F] bf16
    const unsigned short* __restrict__ w2t,   // [E][D][F] bf16
    const int* __restrict__ cnt, const int* __restrict__ lists,
    const float* __restrict__ wts,
    float* __restrict__ yws)                  // [2*NTOK][D] fp32
{
    int e    = blockIdx.y >> 6;
    int mb   = blockIdx.y & 63;
    int n0   = blockIdx.x * 64;               // d tile base
    int ce   = cnt[e];
    int row0 = mb * 64;
    if (row0 >= ce) return;

    __shared__ int   s_slot[64];
    __shared__ float s_w[64];
    __shared__ char  sA[64 * 128];
    __shared__ char  sB[64 * 128];

    int tid = threadIdx.x;
    if (tid < 64) {
        int r  = row0 + tid;
        int sl = (r < ce) ? lists[e * CAP + r] : lists[e * CAP + row0];
        s_slot[tid] = sl;
        s_w[tid]    = wts[sl];
    }
    __syncthreads();

    int lane = tid & 63;
    int wv   = tid >> 6;
    int wm   = wv >> 1, wn = wv & 1;

    f32x4 acc[2][2];
#pragma unroll
    for (int i = 0; i < 2; ++i)
#pragma unroll
        for (int j = 0; j < 2; ++j) acc[i][j] = (f32x4)0.f;

    int lr = tid >> 2;
    int lq = tid & 3;

    const unsigned short* ar  = act + (size_t)s_slot[lr] * FF;
    const unsigned short* w2p = w2t + ((size_t)e * DIM + n0 + lr) * FF;

    for (int kc = 0; kc < FF; kc += 64) {
#pragma unroll
        for (int h = 0; h < 2; ++h) {
            int dl = lq * 16 + h * 8;
            int ba = (lr * 128 + dl * 2) ^ ((lr & 7) << 4);
            *(short8*)(sA + ba) = *(const short8*)(ar  + kc + dl);
            *(short8*)(sB + ba) = *(const short8*)(w2p + kc + dl);
        }
        __syncthreads();

#pragma unroll
        for (int ks = 0; ks < 2; ++ks) {
            short8 af[2], bf[2];
#pragma unroll
            for (int mi = 0; mi < 2; ++mi) {
                int row = wm * 32 + mi * 16 + (lane & 15);
                int ba  = (row * 128 + ks * 64 + (lane >> 4) * 16) ^ ((row & 7) << 4);
                af[mi] = *(const short8*)(sA + ba);
            }
#pragma unroll
            for (int ni = 0; ni < 2; ++ni) {
                int row = wn * 32 + ni * 16 + (lane & 15);
                int ba  = (row * 128 + ks * 64 + (lane >> 4) * 16) ^ ((row & 7) << 4);
                bf[ni] = *(const short8*)(sB + ba);
            }
#pragma unroll
            for (int mi = 0; mi < 2; ++mi)
#pragma unroll
                for (int ni = 0; ni < 2; ++ni)
                    acc[mi][ni] = __builtin_amdgcn_mfma_f32_16x16x32_bf16(af[mi], bf[ni], acc[mi][ni], 0, 0, 0);
        }
        __syncthreads();
    }

#pragma unroll
    for (int mi = 0; mi < 2; ++mi) {
#pragma unroll
        for (int r = 0; r < 4; ++r) {
            int rg = wm * 32 + mi * 16 + (lane >> 4) * 4 + r;
            if (row0 + rg < ce) {
                float w  = s_w[rg];
                int slot = s_slot[rg];
#pragma unroll
                for (int ni = 0; ni < 2; ++ni) {
                    int dd = n0 + wn * 32 + ni * 16 + (lane & 15);
                    yws[(size_t)slot * DIM + dd] = acc[mi][ni][r] * w;
                }
            }
        }
    }
}

// ---------------- combine: out[t] = yws[2t] + yws[2t+1] ----------------
__global__ __launch_bounds__(256) void moe_combine(
    const float* __restrict__ yws, float* __restrict__ out)
{
    int i = blockIdx.x * 256 + threadIdx.x;          // float4 index
    int t  = i >> 7;                                  // 128 float4 per token row
    int d4 = (i & 127) * 4;
    const float4* y0 = (const float4*)(yws + ((size_t)(2 * t)     * DIM + d4));
    const float4* y1 = (const float4*)(yws + ((size_t)(2 * t + 1) * DIM + d4));
    float4 a = *y0, b = *y1;
    float4 o = make_float4(a.x + b.x, a.y + b.y, a.z + b.z, a.w + b.w);
    *(float4*)(out + (size_t)t * DIM + d4) = o;
}

// ---------------- launcher ----------------
extern "C" void kernel_launch(void* const* d_in, const int* in_sizes, int n_in,
                              void* d_out, int out_size, void* d_ws, size_t ws_size,
                              hipStream_t stream)
{
    const float* x  = (const float*)d_in[0];
    const float* wg = (const float*)d_in[1];
    const float* w1 = (const float*)d_in[2];
    const float* w2 = (const float*)d_in[3];   // note: W2 comes before W3 in dict order
    const float* w3 = (const float*)d_in[4];
    const float* b3 = (const float*)d_in[5];
    float* out = (float*)d_out;
    char*  ws  = (char*)d_ws;

    // workspace layout
    int*   cnt   = (int*)ws;                               // 32 B
    int*   lists = (int*)(ws + 256);                       // 8*4096*4 = 128 KiB
    float* wts   = (float*)(ws + 256 + NE * CAP * 4);      // 8192*4 = 32 KiB
    size_t off   = 256 + (size_t)NE * CAP * 4 + (size_t)NTOK * 2 * 4;   // 164096 (256-aligned)
    unsigned short* w1t = (unsigned short*)(ws + off);                      // 12.58 MB
    unsigned short* w3t = w1t + (size_t)NE * FF * DIM;                      // 12.58 MB
    unsigned short* w2t = w3t + (size_t)NE * FF * DIM;                      // 12.58 MB
    unsigned short* act = (unsigned short*)(w2t + (size_t)NE * DIM * FF);   // 25.17 MB
    // yws (16.78 MB) aliases the W1T/W3T region: FFN2/combine no longer need W1T/W3T
    float* yws = (float*)(ws + off);

    hipMemsetAsync(cnt, 0, NE * sizeof(int), stream);

    moe_router<<<NTOK / 4, 256, 0, stream>>>(x, wg, cnt, lists, wts);

    dim3 tgA(FF / 64, DIM / 64, NE);   // W1,W3: [512][1536] -> [1536][512]
    transpose_cvt<<<tgA, 256, 0, stream>>>(w1, w1t, DIM, FF);
    transpose_cvt<<<tgA, 256, 0, stream>>>(w3, w3t, DIM, FF);
    dim3 tgB(DIM / 64, FF / 64, NE);   // W2: [1536][512] -> [512][1536]
    transpose_cvt<<<tgB, 256, 0, stream>>>(w2, w2t, FF, DIM);

    dim3 g1(FF / 64, NE * 64);
    moe_ffn1<<<g1, 256, 0, stream>>>(x, w1t, w3t, b3, cnt, lists, act);

    dim3 g2(DIM / 64, NE * 64);
    moe_ffn2<<<g2, 256, 0, stream>>>(act, w2t, cnt, lists, wts, yws);

    moe_combine<<<(NTOK * DIM / 4) / 256, 256, 0, stream>>>(yws, out);
}

// Round 2
// 265.967 us; speedup vs baseline: 1.3427x; 1.3427x over previous
//
#include <hip/hip_runtime.h>

// ---------------- problem constants ----------------
constexpr int NTOK = 4096;    // B*S
constexpr int DIM  = 512;     // D
constexpr int FF   = 1536;    // F
constexpr int NE   = 8;       // experts
constexpr int CAP  = 4096;    // per-expert list capacity (worst case)

typedef __attribute__((ext_vector_type(8))) short short8;   // 8 bf16 = 4 VGPR
typedef __attribute__((ext_vector_type(4))) float f32x4;    // MFMA acc

static __device__ __forceinline__ unsigned short f2bf(float f) {
    unsigned int x = __float_as_uint(f);
    unsigned int r = x + 0x7fffu + ((x >> 16) & 1u);   // RNE
    return (unsigned short)(r >> 16);
}

// async global->LDS, 16B per lane; LDS dest = wave-uniform base + lane*16
static __device__ __forceinline__ void gload_lds16(const void* g, void* l) {
    __builtin_amdgcn_global_load_lds(
        (const __attribute__((address_space(1))) unsigned int*)g,
        (__attribute__((address_space(3))) unsigned int*)l, 16, 0, 0);
}

// ---------------- router: logits, top-2, softmax weights (NO atomics) ----------------
__global__ __launch_bounds__(256) void moe_router(
    const float* __restrict__ x, const float* __restrict__ wg,
    int* __restrict__ eidx, float* __restrict__ wts)
{
    int lane = threadIdx.x & 63;
    int wave = threadIdx.x >> 6;
    int tok  = blockIdx.x * 4 + wave;

    float acc[NE];
#pragma unroll
    for (int e = 0; e < NE; ++e) acc[e] = 0.f;

    const float* xr = x + (size_t)tok * DIM;
#pragma unroll
    for (int i = 0; i < DIM / 64; ++i) {
        int d = i * 64 + lane;
        float xv = xr[d];
        const float4* wr = (const float4*)(wg + (size_t)d * NE);
        float4 w0 = wr[0], w1 = wr[1];
        acc[0] += xv * w0.x; acc[1] += xv * w0.y; acc[2] += xv * w0.z; acc[3] += xv * w0.w;
        acc[4] += xv * w1.x; acc[5] += xv * w1.y; acc[6] += xv * w1.z; acc[7] += xv * w1.w;
    }
#pragma unroll
    for (int e = 0; e < NE; ++e) {
#pragma unroll
        for (int off = 32; off >= 1; off >>= 1)
            acc[e] += __shfl_xor(acc[e], off, 64);
    }
    if (lane == 0) {
        int i0 = 0; float m0 = acc[0];
#pragma unroll
        for (int e = 1; e < NE; ++e) if (acc[e] > m0) { m0 = acc[e]; i0 = e; }
        int i1 = -1; float m1 = -3.4e38f;
#pragma unroll
        for (int e = 0; e < NE; ++e) if (e != i0 && acc[e] > m1) { m1 = acc[e]; i1 = e; }
        float e1 = expf(m1 - m0);
        float s  = 1.f + e1;
        int s0 = tok * 2, s1 = tok * 2 + 1;
        wts[s0] = 1.f / s;
        wts[s1] = e1 / s;
        eidx[s0] = i0;
        eidx[s1] = i1;
    }
}

// ---------------- build per-expert lists: 8 blocks, ballot counting sort ----------------
__global__ __launch_bounds__(256) void moe_build_lists(
    const int* __restrict__ eidx, int* __restrict__ cnt, int* __restrict__ lists)
{
    int e = blockIdx.x;
    __shared__ int s_base;
    __shared__ int s_wcnt[4];
    if (threadIdx.x == 0) s_base = 0;
    __syncthreads();
    int lane = threadIdx.x & 63, wv = threadIdx.x >> 6;
    for (int c = 0; c < 2 * NTOK; c += 256) {
        int slot = c + threadIdx.x;
        bool m = (eidx[slot] == e);
        unsigned long long bal = __ballot(m);
        if (lane == 0) s_wcnt[wv] = __popcll(bal);
        __syncthreads();
        int wbase = s_base;
        for (int i = 0; i < wv; ++i) wbase += s_wcnt[i];
        if (m) {
            int off = __popcll(bal & ((1ull << lane) - 1ull));
            lists[e * CAP + wbase + off] = slot;
        }
        __syncthreads();
        if (threadIdx.x == 0) s_base += s_wcnt[0] + s_wcnt[1] + s_wcnt[2] + s_wcnt[3];
        __syncthreads();
    }
    if (threadIdx.x == 0) cnt[e] = s_base;
}

// ---------------- x fp32 -> bf16 (linear layout; A-swizzle applied at stage time) ----------------
__global__ __launch_bounds__(256) void cvt_x(
    const float* __restrict__ x, unsigned short* __restrict__ xbf)
{
    int i = (blockIdx.x * 256 + threadIdx.x) * 8;
    float4 a = *(const float4*)(x + i);
    float4 b = *(const float4*)(x + i + 4);
    ushort4 o0, o1;
    o0.x = f2bf(a.x); o0.y = f2bf(a.y); o0.z = f2bf(a.z); o0.w = f2bf(a.w);
    o1.x = f2bf(b.x); o1.y = f2bf(b.y); o1.z = f2bf(b.z); o1.w = f2bf(b.w);
    *(ushort4*)(xbf + i)     = o0;
    *(ushort4*)(xbf + i + 4) = o1;
}

// ---------------- transpose fp32 [R][C] -> bf16 [C][R] PRE-SWIZZLED, per expert ----------------
// out_swz[row][b] = orig[row][b ^ ((row&7)<<4)] within each 128-byte block, so a
// linear global_load_lds copy yields the XOR-swizzled LDS layout (rule #21).
__global__ __launch_bounds__(256) void transpose_cvt(
    const float* __restrict__ in, unsigned short* __restrict__ out, int R, int C)
{
    __shared__ float tile[64][65];
    int c0 = blockIdx.x * 64;
    int r0 = blockIdx.y * 64;
    int z  = blockIdx.z;
    const float* ip = in + (size_t)z * R * C;
    char* op = (char*)(out + (size_t)z * R * C);

    int tr = threadIdx.x >> 4;          // 0..15
    int tc = (threadIdx.x & 15) * 4;    // 0,4,..,60
#pragma unroll
    for (int p = 0; p < 4; ++p) {
        int r = p * 16 + tr;
        float4 v = *(const float4*)(ip + (size_t)(r0 + r) * C + c0 + tc);
        tile[r][tc + 0] = v.x; tile[r][tc + 1] = v.y;
        tile[r][tc + 2] = v.z; tile[r][tc + 3] = v.w;
    }
    __syncthreads();
#pragma unroll
    for (int p = 0; p < 4; ++p) {
        int c = p * 16 + tr;            // output row = original col
        ushort4 o;
        o.x = f2bf(tile[tc + 0][c]);
        o.y = f2bf(tile[tc + 1][c]);
        o.z = f2bf(tile[tc + 2][c]);
        o.w = f2bf(tile[tc + 3][c]);
        int cb = ((r0 + tc) * 2) ^ ((c & 7) << 4);   // XOR touches bits 4-6 only
        *(ushort4*)(op + (size_t)(c0 + c) * (R * 2) + cb) = o;
    }
}

// ---------------- FFN1: act[slot][f] = silu(x W1) * (x W3 + b3) ----------------
// BM=128 rows (gathered slots), BN=64 f-cols, BK=64. 4 waves 2x2 (64 rows x 32 cols each).
__global__ __launch_bounds__(256) void moe_ffn1(
    const unsigned short* __restrict__ xbf,   // [NTOK][D] bf16 linear
    const unsigned short* __restrict__ w1t,   // [E][F][D] bf16 pre-swizzled
    const unsigned short* __restrict__ w3t,   // [E][F][D] bf16 pre-swizzled
    const float* __restrict__ b3,             // [E][F]
    const int* __restrict__ cnt, const int* __restrict__ lists,
    unsigned short* __restrict__ act)         // [2*NTOK][F] bf16 linear
{
    int e    = blockIdx.y >> 5;
    int mb   = blockIdx.y & 31;
    int n0   = blockIdx.x * 64;
    int ce   = cnt[e];
    int row0 = mb * 128;
    if (row0 >= ce) return;

    __shared__ int s_slot[128];
    __shared__ __attribute__((aligned(16))) char sA [128 * 128];
    __shared__ __attribute__((aligned(16))) char sB1[64 * 128];
    __shared__ __attribute__((aligned(16))) char sB3[64 * 128];

    int tid = threadIdx.x;
    if (tid < 128) {
        int r = row0 + tid;
        s_slot[tid] = (r < ce) ? lists[e * CAP + r] : lists[e * CAP + row0];
    }
    __syncthreads();

    int lane = tid & 63;
    int wv   = tid >> 6;
    int wm   = wv >> 1, wn = wv & 1;

    // per-lane staging source pointers (source pre-swizzled for A; weights baked)
    int lrow = lane >> 3;              // row within 8-row group
    int lcol = (lane & 7) * 16;        // byte within 128
    int aswz = lcol ^ (lrow << 4);
    const char* aSrc[4];
#pragma unroll
    for (int i = 0; i < 4; ++i) {
        int rr  = i * 32 + wv * 8 + lrow;
        int tok = s_slot[rr] >> 1;
        aSrc[i] = (const char*)xbf + (size_t)tok * (DIM * 2) + aswz;
    }
    const char* b1Src[2]; const char* b3Src[2];
#pragma unroll
    for (int i = 0; i < 2; ++i) {
        int rr = i * 32 + wv * 8 + lrow;
        size_t rb = ((size_t)e * FF + n0 + rr) * (DIM * 2) + lcol;
        b1Src[i] = (const char*)w1t + rb;
        b3Src[i] = (const char*)w3t + rb;
    }

    f32x4 acch[4][2], accg[4][2];
#pragma unroll
    for (int i = 0; i < 4; ++i)
#pragma unroll
        for (int j = 0; j < 2; ++j) { acch[i][j] = (f32x4)0.f; accg[i][j] = (f32x4)0.f; }

    for (int kc = 0; kc < DIM * 2; kc += 128) {   // kc = K byte offset
#pragma unroll
        for (int i = 0; i < 4; ++i)
            gload_lds16(aSrc[i] + kc, sA + (i * 32 + wv * 8) * 128);
#pragma unroll
        for (int i = 0; i < 2; ++i) {
            gload_lds16(b1Src[i] + kc, sB1 + (i * 32 + wv * 8) * 128);
            gload_lds16(b3Src[i] + kc, sB3 + (i * 32 + wv * 8) * 128);
        }
        __syncthreads();

#pragma unroll
        for (int ks = 0; ks < 2; ++ks) {
            short8 af[4], b1f[2], b3f[2];
#pragma unroll
            for (int mi = 0; mi < 4; ++mi) {
                int row = wm * 64 + mi * 16 + (lane & 15);
                int ba  = row * 128 + ((ks * 64 + (lane >> 4) * 16) ^ ((row & 7) << 4));
                af[mi] = *(const short8*)(sA + ba);
            }
#pragma unroll
            for (int ni = 0; ni < 2; ++ni) {
                int row = wn * 32 + ni * 16 + (lane & 15);
                int ba  = row * 128 + ((ks * 64 + (lane >> 4) * 16) ^ ((row & 7) << 4));
                b1f[ni] = *(const short8*)(sB1 + ba);
                b3f[ni] = *(const short8*)(sB3 + ba);
            }
#pragma unroll
            for (int mi = 0; mi < 4; ++mi)
#pragma unroll
                for (int ni = 0; ni < 2; ++ni) {
                    acch[mi][ni] = __builtin_amdgcn_mfma_f32_16x16x32_bf16(af[mi], b1f[ni], acch[mi][ni], 0, 0, 0);
                    accg[mi][ni] = __builtin_amdgcn_mfma_f32_16x16x32_bf16(af[mi], b3f[ni], accg[mi][ni], 0, 0, 0);
                }
        }
        __syncthreads();
    }

    // epilogue: act = silu(h) * (g + b3)
#pragma unroll
    for (int ni = 0; ni < 2; ++ni) {
        int fcol = n0 + wn * 32 + ni * 16 + (lane & 15);
        float b3v = b3[e * FF + fcol];
#pragma unroll
        for (int mi = 0; mi < 4; ++mi) {
            int rl = wm * 64 + mi * 16 + (lane >> 4) * 4;
#pragma unroll
            for (int r = 0; r < 4; ++r) {
                int rg = rl + r;
                if (row0 + rg < ce) {
                    float h = acch[mi][ni][r];
                    float g = accg[mi][ni][r] + b3v;
                    float a = (h / (1.f + __expf(-h))) * g;
                    act[(size_t)s_slot[rg] * FF + fcol] = f2bf(a);
                }
            }
        }
    }
}

// ---------------- FFN2: yws[slot][d] = w_slot * (act W2) ----------------
__global__ __launch_bounds__(256) void moe_ffn2(
    const unsigned short* __restrict__ act,   // [2*NTOK][F] bf16 linear
    const unsigned short* __restrict__ w2t,   // [E][D][F] bf16 pre-swizzled
    const int* __restrict__ cnt, const int* __restrict__ lists,
    const float* __restrict__ wts,
    float* __restrict__ yws)                  // [2*NTOK][D] fp32
{
    int e    = blockIdx.y >> 5;
    int mb   = blockIdx.y & 31;
    int n0   = blockIdx.x * 64;
    int ce   = cnt[e];
    int row0 = mb * 128;
    if (row0 >= ce) return;

    __shared__ int   s_slot[128];
    __shared__ float s_w[128];
    __shared__ __attribute__((aligned(16))) char sA[128 * 128];
    __shared__ __attribute__((aligned(16))) char sB[64 * 128];

    int tid = threadIdx.x;
    if (tid < 128) {
        int r  = row0 + tid;
        int sl = (r < ce) ? lists[e * CAP + r] : lists[e * CAP + row0];
        s_slot[tid] = sl;
        s_w[tid]    = wts[sl];
    }
    __syncthreads();

    int lane = tid & 63;
    int wv   = tid >> 6;
    int wm   = wv >> 1, wn = wv & 1;

    int lrow = lane >> 3;
    int lcol = (lane & 7) * 16;
    int aswz = lcol ^ (lrow << 4);
    const char* aSrc[4];
#pragma unroll
    for (int i = 0; i < 4; ++i) {
        int rr = i * 32 + wv * 8 + lrow;
        aSrc[i] = (const char*)act + (size_t)s_slot[rr] * (FF * 2) + aswz;
    }
    const char* bSrc[2];
#pragma unroll
    for (int i = 0; i < 2; ++i) {
        int rr = i * 32 + wv * 8 + lrow;
        bSrc[i] = (const char*)w2t + ((size_t)e * DIM + n0 + rr) * (FF * 2) + lcol;
    }

    f32x4 acc[4][2];
#pragma unroll
    for (int i = 0; i < 4; ++i)
#pragma unroll
        for (int j = 0; j < 2; ++j) acc[i][j] = (f32x4)0.f;

    for (int kc = 0; kc < FF * 2; kc += 128) {
#pragma unroll
        for (int i = 0; i < 4; ++i)
            gload_lds16(aSrc[i] + kc, sA + (i * 32 + wv * 8) * 128);
#pragma unroll
        for (int i = 0; i < 2; ++i)
            gload_lds16(bSrc[i] + kc, sB + (i * 32 + wv * 8) * 128);
        __syncthreads();

#pragma unroll
        for (int ks = 0; ks < 2; ++ks) {
            short8 af[4], bf[2];
#pragma unroll
            for (int mi = 0; mi < 4; ++mi) {
                int row = wm * 64 + mi * 16 + (lane & 15);
                int ba  = row * 128 + ((ks * 64 + (lane >> 4) * 16) ^ ((row & 7) << 4));
                af[mi] = *(const short8*)(sA + ba);
            }
#pragma unroll
            for (int ni = 0; ni < 2; ++ni) {
                int row = wn * 32 + ni * 16 + (lane & 15);
                int ba  = row * 128 + ((ks * 64 + (lane >> 4) * 16) ^ ((row & 7) << 4));
                bf[ni] = *(const short8*)(sB + ba);
            }
#pragma unroll
            for (int mi = 0; mi < 4; ++mi)
#pragma unroll
                for (int ni = 0; ni < 2; ++ni)
                    acc[mi][ni] = __builtin_amdgcn_mfma_f32_16x16x32_bf16(af[mi], bf[ni], acc[mi][ni], 0, 0, 0);
        }
        __syncthreads();
    }

#pragma unroll
    for (int mi = 0; mi < 4; ++mi) {
#pragma unroll
        for (int r = 0; r < 4; ++r) {
            int rg = wm * 64 + mi * 16 + (lane >> 4) * 4 + r;
            if (row0 + rg < ce) {
                float w  = s_w[rg];
                int slot = s_slot[rg];
#pragma unroll
                for (int ni = 0; ni < 2; ++ni) {
                    int dd = n0 + wn * 32 + ni * 16 + (lane & 15);
                    yws[(size_t)slot * DIM + dd] = acc[mi][ni][r] * w;
                }
            }
        }
    }
}

// ---------------- combine: out[t] = yws[2t] + yws[2t+1] ----------------
__global__ __launch_bounds__(256) void moe_combine(
    const float* __restrict__ yws, float* __restrict__ out)
{
    int i  = blockIdx.x * 256 + threadIdx.x;
    int t  = i >> 7;
    int d4 = (i & 127) * 4;
    const float4* y0 = (const float4*)(yws + ((size_t)(2 * t)     * DIM + d4));
    const float4* y1 = (const float4*)(yws + ((size_t)(2 * t + 1) * DIM + d4));
    float4 a = *y0, b = *y1;
    float4 o = make_float4(a.x + b.x, a.y + b.y, a.z + b.z, a.w + b.w);
    *(float4*)(out + (size_t)t * DIM + d4) = o;
}

// ---------------- launcher ----------------
extern "C" void kernel_launch(void* const* d_in, const int* in_sizes, int n_in,
                              void* d_out, int out_size, void* d_ws, size_t ws_size,
                              hipStream_t stream)
{
    const float* x  = (const float*)d_in[0];
    const float* wg = (const float*)d_in[1];
    const float* w1 = (const float*)d_in[2];
    const float* w2 = (const float*)d_in[3];
    const float* w3 = (const float*)d_in[4];
    const float* b3 = (const float*)d_in[5];
    float* out = (float*)d_out;
    char*  ws  = (char*)d_ws;

    // workspace layout (peak ~63.3 MB, within proven budget)
    int*   cnt   = (int*)ws;                                        // 256 B slot
    int*   lists = (int*)(ws + 256);                                // 128 KiB
    float* wts   = (float*)(ws + 256 + NE * CAP * 4);               // 32 KiB
    int*   eidx  = (int*)(ws + 256 + NE * CAP * 4 + NTOK * 2 * 4);  // 32 KiB
    size_t off   = 256 + (size_t)NE * CAP * 4 + (size_t)NTOK * 2 * 4 * 2;  // 196864

    constexpr size_t WSZ = (size_t)NE * DIM * FF;   // elements per weight tensor
    unsigned short* w2t = (unsigned short*)(ws + off);   // 12.58 MB (transposed AFTER ffn1)
    unsigned short* w1t = w2t + WSZ;                     // 12.58 MB
    unsigned short* w3t = w1t + WSZ;                     // 12.58 MB
    unsigned short* act = w3t + WSZ;                     // 25.17 MB
    unsigned short* xbf = w2t;                           // alias: 4 MB, dead after ffn1
    float*          yws = (float*)w1t;                   // alias: 16.78 MB, after ffn1

    moe_router<<<NTOK / 4, 256, 0, stream>>>(x, wg, eidx, wts);
    moe_build_lists<<<NE, 256, 0, stream>>>(eidx, cnt, lists);
    cvt_x<<<NTOK * DIM / 8 / 256, 256, 0, stream>>>(x, xbf);

    dim3 tgA(FF / 64, DIM / 64, NE);   // W1,W3: [512][1536] -> [1536][512]
    transpose_cvt<<<tgA, 256, 0, stream>>>(w1, w1t, DIM, FF);
    transpose_cvt<<<tgA, 256, 0, stream>>>(w3, w3t, DIM, FF);

    dim3 g1(FF / 64, NE * 32);
    moe_ffn1<<<g1, 256, 0, stream>>>(xbf, w1t, w3t, b3, cnt, lists, act);

    dim3 tgB(DIM / 64, FF / 64, NE);   // W2: [1536][512] -> [512][1536], overwrites xbf
    transpose_cvt<<<tgB, 256, 0, stream>>>(w2, w2t, FF, DIM);

    dim3 g2(DIM / 64, NE * 32);
    moe_ffn2<<<g2, 256, 0, stream>>>(act, w2t, cnt, lists, wts, yws);

    moe_combine<<<(NTOK * DIM / 4) / 256, 256, 0, stream>>>(yws, out);
}

// Round 4
// 222.777 us; speedup vs baseline: 1.6030x; 1.1939x over previous
//
#include <hip/hip_runtime.h>

// ---------------- problem constants ----------------
constexpr int NTOK = 4096;    // B*S
constexpr int DIM  = 512;     // D
constexpr int FF   = 1536;    // F
constexpr int NE   = 8;       // experts

typedef __attribute__((ext_vector_type(8))) short short8;   // 8 bf16 = 4 VGPR
typedef __attribute__((ext_vector_type(4))) float f32x4;    // MFMA acc

static __device__ __forceinline__ unsigned short f2bf(float f) {
    unsigned int x = __float_as_uint(f);
    unsigned int r = x + 0x7fffu + ((x >> 16) & 1u);   // RNE
    return (unsigned short)(r >> 16);
}

// async global->LDS, 16B per lane; LDS dest = wave-uniform base + lane*16
static __device__ __forceinline__ void gload_lds16(const void* g, void* l) {
    __builtin_amdgcn_global_load_lds(
        (const __attribute__((address_space(1))) unsigned int*)g,
        (__attribute__((address_space(3))) unsigned int*)l, 16, 0, 0);
}

// ---------------- router: logits, top-2, softmax weights; also x->bf16 ----------------
__global__ __launch_bounds__(256) void moe_router(
    const float* __restrict__ x, const float* __restrict__ wg,
    int* __restrict__ eidx, float* __restrict__ wts, unsigned short* __restrict__ xbf)
{
    int lane = threadIdx.x & 63;
    int wave = threadIdx.x >> 6;
    int tok  = blockIdx.x * 4 + wave;

    float acc[NE];
#pragma unroll
    for (int e = 0; e < NE; ++e) acc[e] = 0.f;

    const float* xr = x + (size_t)tok * DIM;
    unsigned short* xo = xbf + (size_t)tok * DIM;
#pragma unroll
    for (int i = 0; i < DIM / 64; ++i) {
        int d = i * 64 + lane;
        float xv = xr[d];
        xo[d] = f2bf(xv);
        const float4* wr = (const float4*)(wg + (size_t)d * NE);
        float4 w0 = wr[0], w1 = wr[1];
        acc[0] += xv * w0.x; acc[1] += xv * w0.y; acc[2] += xv * w0.z; acc[3] += xv * w0.w;
        acc[4] += xv * w1.x; acc[5] += xv * w1.y; acc[6] += xv * w1.z; acc[7] += xv * w1.w;
    }
#pragma unroll
    for (int e = 0; e < NE; ++e) {
#pragma unroll
        for (int off = 32; off >= 1; off >>= 1)
            acc[e] += __shfl_xor(acc[e], off, 64);
    }
    if (lane == 0) {
        int i0 = 0; float m0 = acc[0];
#pragma unroll
        for (int e = 1; e < NE; ++e) if (acc[e] > m0) { m0 = acc[e]; i0 = e; }
        int i1 = -1; float m1 = -3.4e38f;
#pragma unroll
        for (int e = 0; e < NE; ++e) if (e != i0 && acc[e] > m1) { m1 = acc[e]; i1 = e; }
        float e1 = expf(m1 - m0);
        float s  = 1.f + e1;
        int s0 = tok * 2, s1 = tok * 2 + 1;
        wts[s0] = 1.f / s;
        wts[s1] = e1 / s;
        eidx[s0] = i0;
        eidx[s1] = i1;
    }
}

// ---------------- phase 1: per-chunk per-expert counts (32 chunks x 256 slots) ----------------
__global__ __launch_bounds__(256) void moe_count(
    const int* __restrict__ eidx, int* __restrict__ pcnt)
{
    __shared__ int s_wc[4][8];
    int tid = threadIdx.x, lane = tid & 63, wv = tid >> 6;
    int e = eidx[blockIdx.x * 256 + tid];
#pragma unroll
    for (int e0 = 0; e0 < 8; ++e0) {
        unsigned long long bal = __ballot(e == e0);
        if (lane == 0) s_wc[wv][e0] = __popcll(bal);
    }
    __syncthreads();
    if (tid < 8)
        pcnt[blockIdx.x * 8 + tid] = s_wc[0][tid] + s_wc[1][tid] + s_wc[2][tid] + s_wc[3][tid];
}

// ---------------- phase 2: scatter slots into compact expert-sorted list ----------------
// clist[ebase[e] + pos] = slot; ebase 8-aligned prefix of counts.
__global__ __launch_bounds__(256) void moe_scatter(
    const int* __restrict__ eidx, const int* __restrict__ pcnt,
    int* __restrict__ clist, int* __restrict__ cnt, int* __restrict__ ebase)
{
    __shared__ int s_all[256];
    __shared__ int s_wc[4][8];
    int tid = threadIdx.x, bx = blockIdx.x;
    int lane = tid & 63, wv = tid >> 6;
    s_all[tid] = pcnt[tid];
    int slot = bx * 256 + tid;
    int e = eidx[slot];
    int myoff = 0;
#pragma unroll
    for (int e0 = 0; e0 < 8; ++e0) {
        unsigned long long bal = __ballot(e == e0);
        if (lane == 0) s_wc[wv][e0] = __popcll(bal);
        if (e == e0) myoff = __popcll(bal & ((1ull << lane) - 1ull));
    }
    __syncthreads();
    int base = 0;
#pragma unroll
    for (int ep = 0; ep < 8; ++ep) {
        int t = 0;
        for (int b = 0; b < 32; ++b) t += s_all[b * 8 + ep];
        if (ep < e) base += (t + 7) & ~7;
    }
    int cbase = 0;
    for (int b = 0; b < bx; ++b) cbase += s_all[b * 8 + e];
    int wbase = 0;
    for (int w = 0; w < wv; ++w) wbase += s_wc[w][e];
    clist[base + cbase + wbase + myoff] = slot;
    if (bx == 0 && tid == 0) {
        int eb = 0;
        for (int ep = 0; ep < 8; ++ep) {
            int t = 0;
            for (int b = 0; b < 32; ++b) t += s_all[b * 8 + ep];
            cnt[ep] = t;
            ebase[ep] = eb;
            eb += (t + 7) & ~7;
        }
    }
}

// ---------------- transpose fp32 [R][C] -> bf16 [C][R] PRE-SWIZZLED, dual tensor ----------------
// out_swz[row][b] = orig[row][b ^ ((row&7)<<4)] within each 128-byte block (rule #21).
__global__ __launch_bounds__(256) void transpose_cvt2(
    const float* __restrict__ inA, unsigned short* __restrict__ outA,
    const float* __restrict__ inB, unsigned short* __restrict__ outB,
    int R, int C)
{
    __shared__ float tile[64][65];
    int c0 = blockIdx.x * 64, r0 = blockIdx.y * 64, z = blockIdx.z;
    const float* in      = (z < 8) ? inA  : inB;
    unsigned short* out  = (z < 8) ? outA : outB;
    int zz = z & 7;
    const float* ip = in + (size_t)zz * R * C;
    char* op = (char*)(out + (size_t)zz * R * C);

    int tr = threadIdx.x >> 4;          // 0..15
    int tc = (threadIdx.x & 15) * 4;    // 0,4,..,60
#pragma unroll
    for (int p = 0; p < 4; ++p) {
        int r = p * 16 + tr;
        float4 v = *(const float4*)(ip + (size_t)(r0 + r) * C + c0 + tc);
        tile[r][tc + 0] = v.x; tile[r][tc + 1] = v.y;
        tile[r][tc + 2] = v.z; tile[r][tc + 3] = v.w;
    }
    __syncthreads();
#pragma unroll
    for (int p = 0; p < 4; ++p) {
        int c = p * 16 + tr;            // output row = original col
        ushort4 o;
        o.x = f2bf(tile[tc + 0][c]);
        o.y = f2bf(tile[tc + 1][c]);
        o.z = f2bf(tile[tc + 2][c]);
        o.w = f2bf(tile[tc + 3][c]);
        int cb = ((r0 + tc) * 2) ^ ((c & 7) << 4);   // XOR touches bits 4-6 only
        *(ushort4*)(op + (size_t)(c0 + c) * (R * 2) + cb) = o;
    }
}

// ---------------- FFN1: act_c[crow][f] = silu(x W1) * (x W3 + b3) ----------------
// BM=128 gathered rows, BN=128 f-cols, BK=64; 4 waves 2x2 (64x64 each).
// Output written compact (crow = ebase[e]+row) and PRE-SWIZZLED for ffn2's staging.
__global__ __launch_bounds__(256, 2) void moe_ffn1(
    const unsigned short* __restrict__ xbf,   // [NTOK][D] bf16 linear
    const unsigned short* __restrict__ w1t,   // [E][F][D] bf16 pre-swizzled
    const unsigned short* __restrict__ w3t,   // [E][F][D] bf16 pre-swizzled
    const float* __restrict__ b3,             // [E][F]
    const int* __restrict__ cnt, const int* __restrict__ ebase,
    const int* __restrict__ clist,
    unsigned short* __restrict__ actc)        // [8256][F] bf16 pre-swizzled
{
    int e    = blockIdx.y >> 5;
    int mb   = blockIdx.y & 31;
    int n0   = blockIdx.x * 128;
    int ce   = cnt[e];
    int row0 = mb * 128;
    if (row0 >= ce) return;
    int eb   = ebase[e];

    __shared__ __attribute__((aligned(16))) char smem[49152];
    __shared__ int s_slot[128];
    char* sA  = smem;                 // 16 KiB: A 128x128B
    char* sB1 = smem + 16384;         // 16 KiB
    char* sB3 = smem + 32768;         // 16 KiB

    int tid = threadIdx.x;
    if (tid < 128) {
        int r = row0 + tid;
        s_slot[tid] = (r < ce) ? clist[eb + r] : clist[eb + row0];
    }
    __syncthreads();

    int lane = tid & 63, wv = tid >> 6;
    int wm = wv >> 1, wn = wv & 1;
    int lrow = lane >> 3;             // 0..7
    int lcol = (lane & 7) * 16;       // 0..112
    int aswz = lcol ^ (lrow << 4);    // per-lane source swizzle for linear xbf

    const char* aSrc[4]; const char* b1Src[4]; const char* b3Src[4];
#pragma unroll
    for (int i = 0; i < 4; ++i) {
        int rr = i * 32 + wv * 8 + lrow;
        aSrc[i] = (const char*)xbf + (size_t)(s_slot[rr] >> 1) * (DIM * 2) + aswz;
        size_t rb = ((size_t)e * FF + n0 + rr) * (DIM * 2) + lcol;   // weights pre-swizzled
        b1Src[i] = (const char*)w1t + rb;
        b3Src[i] = (const char*)w3t + rb;
    }

    f32x4 acch[4][4], accg[4][4];
#pragma unroll
    for (int i = 0; i < 4; ++i)
#pragma unroll
        for (int j = 0; j < 4; ++j) { acch[i][j] = (f32x4)0.f; accg[i][j] = (f32x4)0.f; }

    for (int kc = 0; kc < DIM * 2; kc += 128) {
#pragma unroll
        for (int i = 0; i < 4; ++i) {
            int ro = (i * 32 + wv * 8) * 128;
            gload_lds16(aSrc[i]  + kc, sA  + ro);
            gload_lds16(b1Src[i] + kc, sB1 + ro);
            gload_lds16(b3Src[i] + kc, sB3 + ro);
        }
        __syncthreads();

#pragma unroll
        for (int ks = 0; ks < 2; ++ks) {
            short8 af[4], b1f[4], b3f[4];
#pragma unroll
            for (int mi = 0; mi < 4; ++mi) {
                int row = wm * 64 + mi * 16 + (lane & 15);
                int ba  = row * 128 + ((ks * 64 + (lane >> 4) * 16) ^ ((row & 7) << 4));
                af[mi] = *(const short8*)(sA + ba);
            }
#pragma unroll
            for (int ni = 0; ni < 4; ++ni) {
                int row = wn * 64 + ni * 16 + (lane & 15);
                int ba  = row * 128 + ((ks * 64 + (lane >> 4) * 16) ^ ((row & 7) << 4));
                b1f[ni] = *(const short8*)(sB1 + ba);
                b3f[ni] = *(const short8*)(sB3 + ba);
            }
#pragma unroll
            for (int mi = 0; mi < 4; ++mi)
#pragma unroll
                for (int ni = 0; ni < 4; ++ni) {
                    acch[mi][ni] = __builtin_amdgcn_mfma_f32_16x16x32_bf16(af[mi], b1f[ni], acch[mi][ni], 0, 0, 0);
                    accg[mi][ni] = __builtin_amdgcn_mfma_f32_16x16x32_bf16(af[mi], b3f[ni], accg[mi][ni], 0, 0, 0);
                }
        }
        __syncthreads();   // also guards sE reuse below
    }

    // epilogue: silu(h)*(g+b3) -> LDS tile (bf16 [128][128], 256B rows) -> coalesced stores
    char* sE = smem;
#pragma unroll
    for (int ni = 0; ni < 4; ++ni) {
        int col = wn * 64 + ni * 16 + (lane & 15);
        float b3v = b3[e * FF + n0 + col];
#pragma unroll
        for (int mi = 0; mi < 4; ++mi) {
            int rbase = wm * 64 + mi * 16 + (lane >> 4) * 4;
#pragma unroll
            for (int r = 0; r < 4; ++r) {
                float h = acch[mi][ni][r];
                float g = accg[mi][ni][r] + b3v;
                float a = (h / (1.f + __expf(-h))) * g;
                *(unsigned short*)(sE + (rbase + r) * 256 + col * 2) = f2bf(a);
            }
        }
    }
    __syncthreads();

    int lim = ce - row0;
#pragma unroll
    for (int it = 0; it < 8; ++it) {
        int chunk = it * 256 + tid;        // 2048 chunks = 128 rows x 16
        int row = chunk >> 4, c8 = chunk & 15;
        if (row < lim) {
            int crow = eb + row0 + row;
            // bake XOR-swizzle into act_c so ffn2 stages with plain linear offsets
            size_t dst = (size_t)crow * (FF * 2) + n0 * 2 + ((c8 * 16) ^ ((crow & 7) << 4));
            *(short8*)((char*)actc + dst) = *(const short8*)(sE + row * 256 + c8 * 16);
        }
    }
}

// ---------------- FFN2: yws[slot][d] = w_slot * (act W2) ----------------
// BM=128 compact rows (linear!), BN=64 d-cols, BK=64.
__global__ __launch_bounds__(256) void moe_ffn2(
    const unsigned short* __restrict__ actc,  // [8256][F] bf16 pre-swizzled
    const unsigned short* __restrict__ w2t,   // [E][D][F] bf16 pre-swizzled
    const int* __restrict__ cnt, const int* __restrict__ ebase,
    const int* __restrict__ clist, const float* __restrict__ wts,
    float* __restrict__ yws)                  // [2*NTOK][D] fp32
{
    int e    = blockIdx.y >> 5;
    int mb   = blockIdx.y & 31;
    int n0   = blockIdx.x * 64;
    int ce   = cnt[e];
    int row0 = mb * 128;
    if (row0 >= ce) return;
    int eb   = ebase[e];

    __shared__ __attribute__((aligned(16))) char smem[32768];
    __shared__ int   s_slot[128];
    __shared__ float s_w[128];
    char* sA = smem;                  // 16 KiB
    char* sB = smem + 16384;          // 8 KiB

    int tid = threadIdx.x;
    if (tid < 128) {
        int r  = row0 + tid;
        int sl = (r < ce) ? clist[eb + r] : clist[eb + row0];
        s_slot[tid] = sl;
        s_w[tid]    = wts[sl];
    }
    __syncthreads();

    int lane = tid & 63, wv = tid >> 6;
    int wm = wv >> 1, wn = wv & 1;
    int lrow = lane >> 3;
    int lcol = (lane & 7) * 16;

    const char* aSrc[4];
#pragma unroll
    for (int i = 0; i < 4; ++i) {
        int rr = i * 32 + wv * 8 + lrow;
        int cr = (row0 + rr < ce) ? (eb + row0 + rr) : (eb + row0);  // clamp: stay in-bounds
        aSrc[i] = (const char*)actc + (size_t)cr * (FF * 2) + lcol;  // actc pre-swizzled
    }
    const char* bSrc[2];
#pragma unroll
    for (int i = 0; i < 2; ++i) {
        int rr = i * 32 + wv * 8 + lrow;
        bSrc[i] = (const char*)w2t + ((size_t)e * DIM + n0 + rr) * (FF * 2) + lcol;
    }

    f32x4 acc[4][2];
#pragma unroll
    for (int i = 0; i < 4; ++i)
#pragma unroll
        for (int j = 0; j < 2; ++j) acc[i][j] = (f32x4)0.f;

    for (int kc = 0; kc < FF * 2; kc += 128) {
#pragma unroll
        for (int i = 0; i < 4; ++i)
            gload_lds16(aSrc[i] + kc, sA + (i * 32 + wv * 8) * 128);
#pragma unroll
        for (int i = 0; i < 2; ++i)
            gload_lds16(bSrc[i] + kc, sB + (i * 32 + wv * 8) * 128);
        __syncthreads();

#pragma unroll
        for (int ks = 0; ks < 2; ++ks) {
            short8 af[4], bf[2];
#pragma unroll
            for (int mi = 0; mi < 4; ++mi) {
                int row = wm * 64 + mi * 16 + (lane & 15);
                int ba  = row * 128 + ((ks * 64 + (lane >> 4) * 16) ^ ((row & 7) << 4));
                af[mi] = *(const short8*)(sA + ba);
            }
#pragma unroll
            for (int ni = 0; ni < 2; ++ni) {
                int row = wn * 32 + ni * 16 + (lane & 15);
                int ba  = row * 128 + ((ks * 64 + (lane >> 4) * 16) ^ ((row & 7) << 4));
                bf[ni] = *(const short8*)(sB + ba);
            }
#pragma unroll
            for (int mi = 0; mi < 4; ++mi)
#pragma unroll
                for (int ni = 0; ni < 2; ++ni)
                    acc[mi][ni] = __builtin_amdgcn_mfma_f32_16x16x32_bf16(af[mi], bf[ni], acc[mi][ni], 0, 0, 0);
        }
        __syncthreads();
    }

    // epilogue: scale by routing weight, stage fp32 tile [128][64] in LDS, store float4
    char* sE = smem;
#pragma unroll
    for (int mi = 0; mi < 4; ++mi) {
        int rbase = wm * 64 + mi * 16 + (lane >> 4) * 4;
#pragma unroll
        for (int r = 0; r < 4; ++r) {
            int row = rbase + r;
            float w = s_w[row];
#pragma unroll
            for (int ni = 0; ni < 2; ++ni) {
                int col = wn * 32 + ni * 16 + (lane & 15);
                *(float*)(sE + row * 256 + col * 4) = acc[mi][ni][r] * w;
            }
        }
    }
    __syncthreads();

    int lim = ce - row0;
    // 128 rows x 64 fp32 = 256B/row = 16 float4 chunks/row -> 2048 chunks total.
    // (Round-3 bug: it<2 with chunk>>2/&3 only stored 4 of 16 chunks per row.)
#pragma unroll
    for (int it = 0; it < 8; ++it) {
        int chunk = it * 256 + tid;        // 2048 chunks = 128 rows x 16
        int row = chunk >> 4, c4 = chunk & 15;
        if (row < lim)
            *(float4*)(yws + (size_t)s_slot[row] * DIM + n0 + c4 * 4) =
                *(const float4*)(sE + row * 256 + c4 * 16);
    }
}

// ---------------- combine: out[t] = yws[2t] + yws[2t+1] ----------------
__global__ __launch_bounds__(256) void moe_combine(
    const float* __restrict__ yws, float* __restrict__ out)
{
    int i  = blockIdx.x * 256 + threadIdx.x;
    int t  = i >> 7;
    int d4 = (i & 127) * 4;
    const float4* y0 = (const float4*)(yws + ((size_t)(2 * t)     * DIM + d4));
    const float4* y1 = (const float4*)(yws + ((size_t)(2 * t + 1) * DIM + d4));
    float4 a = *y0, b = *y1;
    float4 o = make_float4(a.x + b.x, a.y + b.y, a.z + b.z, a.w + b.w);
    *(float4*)(out + (size_t)t * DIM + d4) = o;
}

// ---------------- launcher ----------------
extern "C" void kernel_launch(void* const* d_in, const int* in_sizes, int n_in,
                              void* d_out, int out_size, void* d_ws, size_t ws_size,
                              hipStream_t stream)
{
    const float* x  = (const float*)d_in[0];
    const float* wg = (const float*)d_in[1];
    const float* w1 = (const float*)d_in[2];
    const float* w2 = (const float*)d_in[3];
    const float* w3 = (const float*)d_in[4];
    const float* b3 = (const float*)d_in[5];
    float* out = (float*)d_out;
    char*  ws  = (char*)d_ws;

    // small control block
    int*   cnt   = (int*)(ws + 0);        // 8 int
    int*   ebase = (int*)(ws + 64);       // 8 int
    int*   pcnt  = (int*)(ws + 256);      // 256 int
    int*   eidx  = (int*)(ws + 2048);     // 8192 int
    float* wts   = (float*)(ws + 2048 + 32768);            // 8192 f
    int*   clist = (int*)(ws + 2048 + 65536);              // 8256 int
    constexpr size_t OFF_BIG = 102400;
    constexpr size_t WB = (size_t)NE * DIM * FF * 2;       // bytes per weight tensor (bf16)
    unsigned short* w2t  = (unsigned short*)(ws + OFF_BIG);            // 12.58 MB
    unsigned short* w1t  = (unsigned short*)(ws + OFF_BIG + WB);       // 12.58 MB
    unsigned short* w3t  = (unsigned short*)(ws + OFF_BIG + 2 * WB);   // 12.58 MB
    unsigned short* actc = (unsigned short*)(ws + OFF_BIG + 3 * WB);   // 8256*3072B = 25.4 MB
    unsigned short* xbf  = w2t;                 // alias: 4 MB, dead before w2 transpose
    float*          yws  = (float*)w1t;         // alias: 16.78 MB, used after ffn1

    moe_router <<<NTOK / 4, 256, 0, stream>>>(x, wg, eidx, wts, xbf);
    moe_count  <<<32, 256, 0, stream>>>(eidx, pcnt);
    moe_scatter<<<32, 256, 0, stream>>>(eidx, pcnt, clist, cnt, ebase);

    dim3 tgA(FF / 64, DIM / 64, 16);   // W1,W3: [512][1536] -> [1536][512]
    transpose_cvt2<<<tgA, 256, 0, stream>>>(w1, w1t, w3, w3t, DIM, FF);

    dim3 g1(FF / 128, NE * 32);
    moe_ffn1<<<g1, 256, 0, stream>>>(xbf, w1t, w3t, b3, cnt, ebase, clist, actc);

    dim3 tgB(DIM / 64, FF / 64, 8);    // W2: [1536][512] -> [512][1536], overwrites xbf
    transpose_cvt2<<<tgB, 256, 0, stream>>>(w2, w2t, w2, w2t, FF, DIM);

    dim3 g2(DIM / 64, NE * 32);
    moe_ffn2<<<g2, 256, 0, stream>>>(actc, w2t, cnt, ebase, clist, wts, yws);

    moe_combine<<<(NTOK * DIM / 4) / 256, 256, 0, stream>>>(yws, out);
}